// Round 7
// baseline (116.485 us; speedup 1.0000x reference)
//
#include <hip/hip_runtime.h>
#include <hip/hip_bf16.h>

typedef short bf16x8 __attribute__((ext_vector_type(8)));
typedef float f32x4  __attribute__((ext_vector_type(4)));

__device__ __forceinline__ unsigned short f2bf(float f) {
    union { float f; unsigned int u; } v; v.f = f;
    unsigned int u = v.u;
    u += 0x7FFFu + ((u >> 16) & 1u);   // round-to-nearest-even
    return (unsigned short)(u >> 16);
}

__device__ __forceinline__ f32x4 mfma_bf16(bf16x8 a, bf16x8 b, f32x4 c) {
    return __builtin_amdgcn_mfma_f32_16x16x32_bf16(a, b, c, 0, 0, 0);
}

// pack two f32x4 acc tiles (m-tile 0, m-tile 1) into one bf16 fragment under
// the shared k-bijection pi(g,j) = {4g+j | j<4} u {16+4g+(j-4) | j>=4}
__device__ __forceinline__ bf16x8 pack2(f32x4 lo, f32x4 hi) {
    bf16x8 r;
    r[0] = (short)f2bf(lo[0]); r[1] = (short)f2bf(lo[1]);
    r[2] = (short)f2bf(lo[2]); r[3] = (short)f2bf(lo[3]);
    r[4] = (short)f2bf(hi[0]); r[5] = (short)f2bf(hi[1]);
    r[6] = (short)f2bf(hi[2]); r[7] = (short)f2bf(hi[3]);
    return r;
}

// ---------------- prep: transpose + bf16-convert four 256x256 weights ----------------
// dst layout: WT[n][k] = W[k][n], bf16, row-major [256][256]; 4 matrices back to back.
__global__ __launch_bounds__(256) void prep_weights(
    const float* __restrict__ wq, const float* __restrict__ wk,
    const float* __restrict__ wv, const float* __restrict__ wo,
    unsigned short* __restrict__ wt)
{
    __shared__ float tile[64][65];
    const int bx  = blockIdx.x;        // 0..63
    const int mat = bx >> 4;
    const int t   = bx & 15;
    const int tn  = t >> 2, tk = t & 3;   // 64x64 tile coords
    const float* src = (mat == 0) ? wq : (mat == 1) ? wk : (mat == 2) ? wv : wo;
    unsigned short* dst = wt + mat * 65536;
    const int tid = threadIdx.x;
#pragma unroll
    for (int j = 0; j < 16; ++j) {
        int idx = tid + 256 * j;
        int r = idx >> 6, c = idx & 63;
        tile[r][c] = src[(tk * 64 + r) * 256 + tn * 64 + c];
    }
    __syncthreads();
#pragma unroll
    for (int j = 0; j < 16; ++j) {
        int idx = tid + 256 * j;
        int r = idx >> 6, c = idx & 63;
        dst[(tn * 64 + r) * 256 + tk * 64 + c] = f2bf(tile[c][r]);
    }
}

// ---------------- fused window attention, register-resident attention ----------------
// grid = 1024 (= 16 b * 64 h), block = 512 (8 waves). Each WG owns 64 tokens.
// wave w = head w. Q^T,K^T via swapped mfma operands so QK^T/softmax/PV stay in
// registers; only X and the merged head outputs transit LDS.
// ALL phases accumulate through ONE flat f32x4 facc[8] (32 regs, static indices):
// the backend sizes the AGPR segment to total acc demand without coalescing
// disjoint lifetimes (r4/r6 evidence: acc=half of budget, arch spills). 32 acc
// slots -> ~200 arch regs free -> no scratch.
#define XS_STRIDE 264   // 256 + 8 pad shorts

__global__ __launch_bounds__(512, 2) void win_attn(
    const float* __restrict__ x,
    const unsigned short* __restrict__ wt,   // WqT,WkT,WvT,WoT each 256*256 bf16
    const float* __restrict__ bo,
    float* __restrict__ out)                 // f32 output
{
    __shared__ unsigned short lds[33792];    // 66 KiB
    unsigned short* Xs = lds;                // [64][264]
    unsigned short* Os = lds + 16896;        // [64][264]

    const int tid  = threadIdx.x;
    const int wid  = tid >> 6;               // 0..7 (= head)
    const int lane = tid & 63;
    const int l15  = lane & 15;
    const int g    = lane >> 4;              // 0..3

    const unsigned short* WQ = wt;
    const unsigned short* WK = wt + 65536;
    const unsigned short* WV = wt + 2 * 65536;
    const unsigned short* WO = wt + 3 * 65536;

    const long long base_tok = (long long)blockIdx.x * 64;
    const float* xblk = x + base_tok * 256;

    const f32x4 fz = {0.f, 0.f, 0.f, 0.f};
    f32x4 facc[8];                           // shared accumulator pool, all phases

    // ---- phase 0: stage x row-block as bf16 in LDS ----
#pragma unroll
    for (int i = 0; i < 8; ++i) {
        int p   = tid + i * 512;             // float4 index, 0..4095
        int tok = p >> 6;
        int col = (p & 63) * 4;
        float4 v = reinterpret_cast<const float4*>(xblk)[p];
        ushort4 h;
        h.x = f2bf(v.x); h.y = f2bf(v.y); h.z = f2bf(v.z); h.w = f2bf(v.w);
        *reinterpret_cast<ushort4*>(&Xs[tok * XS_STRIDE + col]) = h;
    }
    __syncthreads();

    // ---- phase 1a: Q^T = mfma(A = WqT rows (m=d-channel), B = Xs rows (n=token)) ----
    // facc[mt*4+nt]; D: lane -> token = nt*16 + l15, d = mt*16 + 4g + r
    bf16x8 qtf[4];
    {
#pragma unroll
        for (int i = 0; i < 8; ++i) facc[i] = fz;
#pragma unroll
        for (int kk = 0; kk < 8; ++kk) {
            bf16x8 aw[2], bx[4];
#pragma unroll
            for (int mt = 0; mt < 2; ++mt)
                aw[mt] = *reinterpret_cast<const bf16x8*>(&WQ[(wid * 32 + mt * 16 + l15) * 256 + kk * 32 + g * 8]);
#pragma unroll
            for (int nt = 0; nt < 4; ++nt)
                bx[nt] = *reinterpret_cast<const bf16x8*>(&Xs[(nt * 16 + l15) * XS_STRIDE + kk * 32 + g * 8]);
#pragma unroll
            for (int mt = 0; mt < 2; ++mt)
#pragma unroll
                for (int nt = 0; nt < 4; ++nt)
                    facc[mt * 4 + nt] = mfma_bf16(aw[mt], bx[nt], facc[mt * 4 + nt]);
        }
#pragma unroll
        for (int nt = 0; nt < 4; ++nt) qtf[nt] = pack2(facc[nt], facc[4 + nt]);
    }

    // ---- phase 1b: K^T, same structure, same facc slots ----
    bf16x8 ktf[4];
    {
#pragma unroll
        for (int i = 0; i < 8; ++i) facc[i] = fz;
#pragma unroll
        for (int kk = 0; kk < 8; ++kk) {
            bf16x8 aw[2], bx[4];
#pragma unroll
            for (int mt = 0; mt < 2; ++mt)
                aw[mt] = *reinterpret_cast<const bf16x8*>(&WK[(wid * 32 + mt * 16 + l15) * 256 + kk * 32 + g * 8]);
#pragma unroll
            for (int nt = 0; nt < 4; ++nt)
                bx[nt] = *reinterpret_cast<const bf16x8*>(&Xs[(nt * 16 + l15) * XS_STRIDE + kk * 32 + g * 8]);
#pragma unroll
            for (int mt = 0; mt < 2; ++mt)
#pragma unroll
                for (int nt = 0; nt < 4; ++nt)
                    facc[mt * 4 + nt] = mfma_bf16(aw[mt], bx[nt], facc[mt * 4 + nt]);
        }
#pragma unroll
        for (int nt = 0; nt < 4; ++nt) ktf[nt] = pack2(facc[nt], facc[4 + nt]);
    }

    // ---- phase 2: S^T = K Q^T, softmax over k_tok (in facc[0..3]), P frags ----
    // facc[mi]: lane -> k_tok = mi*16 + 4g + r, q = ni*16 + l15
    constexpr float kC = 0.25501817419392105f;  // (1/sqrt(32)) * log2(e)
    bf16x8 ptf[4][2];                            // [q-tile][kk]  (PV A-fragments)
#pragma unroll
    for (int ni = 0; ni < 4; ++ni) {
#pragma unroll
        for (int mi = 0; mi < 4; ++mi)
            facc[mi] = mfma_bf16(ktf[mi], qtf[ni], fz);
        float m = facc[0][0];
#pragma unroll
        for (int mi = 0; mi < 4; ++mi)
#pragma unroll
            for (int r = 0; r < 4; ++r) m = fmaxf(m, facc[mi][r]);
        m = fmaxf(m, __shfl_xor(m, 16));
        m = fmaxf(m, __shfl_xor(m, 32));
        float sum = 0.f;
#pragma unroll
        for (int mi = 0; mi < 4; ++mi)
#pragma unroll
            for (int r = 0; r < 4; ++r) {
                facc[mi][r] = exp2f((facc[mi][r] - m) * kC);   // in place
                sum += facc[mi][r];
            }
        sum += __shfl_xor(sum, 16);
        sum += __shfl_xor(sum, 32);
        float inv = 1.0f / sum;
#pragma unroll
        for (int kk = 0; kk < 2; ++kk) {
            bf16x8 t;
#pragma unroll
            for (int j = 0; j < 4; ++j) {
                t[j]     = (short)f2bf(facc[2 * kk][j] * inv);
                t[4 + j] = (short)f2bf(facc[2 * kk + 1][j] * inv);
            }
            ptf[ni][kk] = t;
        }
    }

    // ---- phase 3: V = X Wv (normal orientation), one d-half at a time -> PV B-frags ----
    bf16x8 vtf[2][2];                            // [kk][d-tile]
#pragma unroll
    for (int ni = 0; ni < 2; ++ni) {             // d-half
#pragma unroll
        for (int mi = 0; mi < 4; ++mi) facc[mi] = fz;
#pragma unroll
        for (int kk = 0; kk < 8; ++kk) {
            bf16x8 b = *reinterpret_cast<const bf16x8*>(&WV[(wid * 32 + ni * 16 + l15) * 256 + kk * 32 + g * 8]);
#pragma unroll
            for (int mi = 0; mi < 4; ++mi) {
                bf16x8 a = *reinterpret_cast<const bf16x8*>(&Xs[(mi * 16 + l15) * XS_STRIDE + kk * 32 + g * 8]);
                facc[mi] = mfma_bf16(a, b, facc[mi]);
            }
        }
#pragma unroll
        for (int kk = 0; kk < 2; ++kk)
            vtf[kk][ni] = pack2(facc[2 * kk], facc[2 * kk + 1]);
    }

    // ---- phase 4: O = P V, all-register operands; facc[mi*2+ni] ----
    {
#pragma unroll
        for (int i = 0; i < 8; ++i) facc[i] = fz;
#pragma unroll
        for (int kk = 0; kk < 2; ++kk)
#pragma unroll
            for (int mi = 0; mi < 4; ++mi)
#pragma unroll
                for (int ni = 0; ni < 2; ++ni)
                    facc[mi * 2 + ni] = mfma_bf16(ptf[mi][kk], vtf[kk][ni], facc[mi * 2 + ni]);

        // merged attention output Os[token][head*32+d] (separate region: no WAR barrier)
#pragma unroll
        for (int mi = 0; mi < 4; ++mi)
#pragma unroll
            for (int ni = 0; ni < 2; ++ni)
#pragma unroll
                for (int r = 0; r < 4; ++r)
                    Os[(mi * 16 + g * 4 + r) * XS_STRIDE + wid * 32 + ni * 16 + l15] = f2bf(facc[mi * 2 + ni][r]);
    }
    __syncthreads();

    // ---- phase 5: Y = Os @ Wo + bo, f32 store; facc[mi*2+ni] ----
    {
#pragma unroll
        for (int i = 0; i < 8; ++i) facc[i] = fz;
#pragma unroll
        for (int kk = 0; kk < 8; ++kk) {
            bf16x8 a[4], b[2];
#pragma unroll
            for (int mi = 0; mi < 4; ++mi)
                a[mi] = *reinterpret_cast<const bf16x8*>(&Os[(mi * 16 + l15) * XS_STRIDE + kk * 32 + g * 8]);
#pragma unroll
            for (int ni = 0; ni < 2; ++ni)
                b[ni] = *reinterpret_cast<const bf16x8*>(&WO[(wid * 32 + ni * 16 + l15) * 256 + kk * 32 + g * 8]);
#pragma unroll
            for (int mi = 0; mi < 4; ++mi)
#pragma unroll
                for (int ni = 0; ni < 2; ++ni)
                    facc[mi * 2 + ni] = mfma_bf16(a[mi], b[ni], facc[mi * 2 + ni]);
        }
#pragma unroll
        for (int mi = 0; mi < 4; ++mi) {
#pragma unroll
            for (int ni = 0; ni < 2; ++ni) {
                int col = wid * 32 + ni * 16 + l15;
                float bv = bo[col];
#pragma unroll
                for (int r = 0; r < 4; ++r) {
                    int row = mi * 16 + g * 4 + r;
                    out[(base_tok + row) * 256 + col] = facc[mi * 2 + ni][r] + bv;
                }
            }
        }
    }
}

extern "C" void kernel_launch(void* const* d_in, const int* in_sizes, int n_in,
                              void* d_out, int out_size, void* d_ws, size_t ws_size,
                              hipStream_t stream) {
    const float* x  = (const float*)d_in[0];
    const float* wq = (const float*)d_in[1];
    const float* wk = (const float*)d_in[2];
    const float* wv = (const float*)d_in[3];
    const float* wo = (const float*)d_in[4];
    const float* bo = (const float*)d_in[5];
    unsigned short* wt = (unsigned short*)d_ws;      // 4 * 256*256 bf16 = 512 KiB
    float* out = (float*)d_out;                      // f32 output

    prep_weights<<<64, 256, 0, stream>>>(wq, wk, wv, wo, wt);
    win_attn<<<1024, 512, 0, stream>>>(x, wt, bo, out);
}

// Round 8
// 107.661 us; speedup vs baseline: 1.0820x; 1.0820x over previous
//
#include <hip/hip_runtime.h>
#include <hip/hip_bf16.h>

typedef short bf16x8 __attribute__((ext_vector_type(8)));
typedef float f32x4  __attribute__((ext_vector_type(4)));

__device__ __forceinline__ unsigned short f2bf(float f) {
    union { float f; unsigned int u; } v; v.f = f;
    unsigned int u = v.u;
    u += 0x7FFFu + ((u >> 16) & 1u);   // round-to-nearest-even
    return (unsigned short)(u >> 16);
}

__device__ __forceinline__ f32x4 mfma_bf16(bf16x8 a, bf16x8 b, f32x4 c) {
    return __builtin_amdgcn_mfma_f32_16x16x32_bf16(a, b, c, 0, 0, 0);
}

// pack two f32x4 acc tiles (m-tile 0, m-tile 1) into one bf16 fragment under
// the shared k-bijection pi(g,j) = {4g+j | j<4} u {16+4g+(j-4) | j>=4}
__device__ __forceinline__ bf16x8 pack2(f32x4 lo, f32x4 hi) {
    bf16x8 r;
    r[0] = (short)f2bf(lo[0]); r[1] = (short)f2bf(lo[1]);
    r[2] = (short)f2bf(lo[2]); r[3] = (short)f2bf(lo[3]);
    r[4] = (short)f2bf(hi[0]); r[5] = (short)f2bf(hi[1]);
    r[6] = (short)f2bf(hi[2]); r[7] = (short)f2bf(hi[3]);
    return r;
}

// ---------------- prep: transpose + bf16-convert four 256x256 weights ----------------
__global__ __launch_bounds__(256) void prep_weights(
    const float* __restrict__ wq, const float* __restrict__ wk,
    const float* __restrict__ wv, const float* __restrict__ wo,
    unsigned short* __restrict__ wt)
{
    __shared__ float tile[64][65];
    const int bx  = blockIdx.x;        // 0..63
    const int mat = bx >> 4;
    const int t   = bx & 15;
    const int tn  = t >> 2, tk = t & 3;   // 64x64 tile coords
    const float* src = (mat == 0) ? wq : (mat == 1) ? wk : (mat == 2) ? wv : wo;
    unsigned short* dst = wt + mat * 65536;
    const int tid = threadIdx.x;
#pragma unroll
    for (int j = 0; j < 16; ++j) {
        int idx = tid + 256 * j;
        int r = idx >> 6, c = idx & 63;
        tile[r][c] = src[(tk * 64 + r) * 256 + tn * 64 + c];
    }
    __syncthreads();
#pragma unroll
    for (int j = 0; j < 16; ++j) {
        int idx = tid + 256 * j;
        int r = idx >> 6, c = idx & 63;
        dst[(tn * 64 + r) * 256 + tk * 64 + c] = f2bf(tile[c][r]);
    }
}

// ---------------- fused window attention, register-resident attention ----------------
// grid = 1024 (= 16 b * 64 h), block = 512 (8 waves). Each WG owns 64 tokens.
// wave w = head w. Phase order chosen for a FLAT register profile (r7 lesson:
// the (512,2) arch segment caps at 128; ptf[4][2] made peak ~130 -> spill):
//   V -> Q^T -> K^T -> { per q-tile: S^T, softmax, pa[2], PV, Os write } -> Y.
// P exists only 8 regs at a time; peak arch live ~90. 2 barriers total.
#define XS_STRIDE 264   // 256 + 8 pad shorts

__global__ __launch_bounds__(512, 2) void win_attn(
    const float* __restrict__ x,
    const unsigned short* __restrict__ wt,   // WqT,WkT,WvT,WoT each 256*256 bf16
    const float* __restrict__ bo,
    float* __restrict__ out)                 // f32 output
{
    __shared__ unsigned short lds[33792];    // 66 KiB
    unsigned short* Xs = lds;                // [64][264]
    unsigned short* Os = lds + 16896;        // [64][264]

    const int tid  = threadIdx.x;
    const int wid  = tid >> 6;               // 0..7 (= head)
    const int lane = tid & 63;
    const int l15  = lane & 15;
    const int g    = lane >> 4;              // 0..3

    const unsigned short* WQ = wt;
    const unsigned short* WK = wt + 65536;
    const unsigned short* WV = wt + 2 * 65536;
    const unsigned short* WO = wt + 3 * 65536;

    const long long base_tok = (long long)blockIdx.x * 64;
    const float* xblk = x + base_tok * 256;

    const f32x4 fz = {0.f, 0.f, 0.f, 0.f};

    // ---- phase 0: stage x row-block as bf16 in LDS ----
#pragma unroll
    for (int i = 0; i < 8; ++i) {
        int p   = tid + i * 512;             // float4 index, 0..4095
        int tok = p >> 6;
        int col = (p & 63) * 4;
        float4 v = reinterpret_cast<const float4*>(xblk)[p];
        ushort4 h;
        h.x = f2bf(v.x); h.y = f2bf(v.y); h.z = f2bf(v.z); h.w = f2bf(v.w);
        *reinterpret_cast<ushort4*>(&Xs[tok * XS_STRIDE + col]) = h;
    }
    __syncthreads();

    // ---- phase 1: V = X Wv (normal orientation), one d-half at a time -> PV B-frags ----
    bf16x8 vtf[2][2];                            // [k-half][d-half], 16 regs
#pragma unroll
    for (int dh = 0; dh < 2; ++dh) {
        f32x4 vacc[4] = {fz, fz, fz, fz};
#pragma unroll
        for (int kk = 0; kk < 8; ++kk) {
            bf16x8 b = *reinterpret_cast<const bf16x8*>(&WV[(wid * 32 + dh * 16 + l15) * 256 + kk * 32 + g * 8]);
#pragma unroll
            for (int mi = 0; mi < 4; ++mi) {
                bf16x8 a = *reinterpret_cast<const bf16x8*>(&Xs[(mi * 16 + l15) * XS_STRIDE + kk * 32 + g * 8]);
                vacc[mi] = mfma_bf16(a, b, vacc[mi]);
            }
        }
        vtf[0][dh] = pack2(vacc[0], vacc[1]);
        vtf[1][dh] = pack2(vacc[2], vacc[3]);
    }

    // ---- phase 2: Q^T = mfma(A = WqT rows (m=d), B = Xs rows (n=token)) ----
    // D: lane -> token = nt*16 + l15, d = mt*16 + 4g + r
    bf16x8 qtf[4];
    {
        f32x4 qt[2][4] = {{fz, fz, fz, fz}, {fz, fz, fz, fz}};
#pragma unroll
        for (int kk = 0; kk < 8; ++kk) {
            bf16x8 aw[2], bx[4];
#pragma unroll
            for (int mt = 0; mt < 2; ++mt)
                aw[mt] = *reinterpret_cast<const bf16x8*>(&WQ[(wid * 32 + mt * 16 + l15) * 256 + kk * 32 + g * 8]);
#pragma unroll
            for (int nt = 0; nt < 4; ++nt)
                bx[nt] = *reinterpret_cast<const bf16x8*>(&Xs[(nt * 16 + l15) * XS_STRIDE + kk * 32 + g * 8]);
#pragma unroll
            for (int mt = 0; mt < 2; ++mt)
#pragma unroll
                for (int nt = 0; nt < 4; ++nt)
                    qt[mt][nt] = mfma_bf16(aw[mt], bx[nt], qt[mt][nt]);
        }
#pragma unroll
        for (int nt = 0; nt < 4; ++nt) qtf[nt] = pack2(qt[0][nt], qt[1][nt]);
    }

    // ---- phase 3: K^T, same structure ----
    bf16x8 ktf[4];
    {
        f32x4 kt[2][4] = {{fz, fz, fz, fz}, {fz, fz, fz, fz}};
#pragma unroll
        for (int kk = 0; kk < 8; ++kk) {
            bf16x8 aw[2], bx[4];
#pragma unroll
            for (int mt = 0; mt < 2; ++mt)
                aw[mt] = *reinterpret_cast<const bf16x8*>(&WK[(wid * 32 + mt * 16 + l15) * 256 + kk * 32 + g * 8]);
#pragma unroll
            for (int nt = 0; nt < 4; ++nt)
                bx[nt] = *reinterpret_cast<const bf16x8*>(&Xs[(nt * 16 + l15) * XS_STRIDE + kk * 32 + g * 8]);
#pragma unroll
            for (int mt = 0; mt < 2; ++mt)
#pragma unroll
                for (int nt = 0; nt < 4; ++nt)
                    kt[mt][nt] = mfma_bf16(aw[mt], bx[nt], kt[mt][nt]);
        }
#pragma unroll
        for (int nt = 0; nt < 4; ++nt) ktf[nt] = pack2(kt[0][nt], kt[1][nt]);
    }

    // ---- phase 4: per q-tile ni: S^T = K Q^T, softmax over k_tok, P frags, PV, Os ----
    // st[mi]: lane -> k_tok = mi*16 + 4g + r, q = ni*16 + l15
    constexpr float kC = 0.25501817419392105f;  // (1/sqrt(32)) * log2(e)
#pragma unroll
    for (int ni = 0; ni < 4; ++ni) {
        f32x4 st[4];
#pragma unroll
        for (int mi = 0; mi < 4; ++mi)
            st[mi] = mfma_bf16(ktf[mi], qtf[ni], fz);
        float m = st[0][0];
#pragma unroll
        for (int mi = 0; mi < 4; ++mi)
#pragma unroll
            for (int r = 0; r < 4; ++r) m = fmaxf(m, st[mi][r]);
        m = fmaxf(m, __shfl_xor(m, 16));
        m = fmaxf(m, __shfl_xor(m, 32));
        float sum = 0.f;
#pragma unroll
        for (int mi = 0; mi < 4; ++mi)
#pragma unroll
            for (int r = 0; r < 4; ++r) {
                st[mi][r] = exp2f((st[mi][r] - m) * kC);   // in place
                sum += st[mi][r];
            }
        sum += __shfl_xor(sum, 16);
        sum += __shfl_xor(sum, 32);
        float inv = 1.0f / sum;
        bf16x8 pa[2];                            // P fragment for THIS q-tile only
#pragma unroll
        for (int kk = 0; kk < 2; ++kk) {
            bf16x8 t;
#pragma unroll
            for (int j = 0; j < 4; ++j) {
                t[j]     = (short)f2bf(st[2 * kk][j] * inv);
                t[4 + j] = (short)f2bf(st[2 * kk + 1][j] * inv);
            }
            pa[kk] = t;
        }
        // PV for this q-tile: O rows ni*16.. (m=q-token, n=d within half dh)
        f32x4 oacc[2] = {fz, fz};
#pragma unroll
        for (int kk = 0; kk < 2; ++kk)
#pragma unroll
            for (int dh = 0; dh < 2; ++dh)
                oacc[dh] = mfma_bf16(pa[kk], vtf[kk][dh], oacc[dh]);
        // merged attention output Os[token][head*32+d]
#pragma unroll
        for (int dh = 0; dh < 2; ++dh)
#pragma unroll
            for (int r = 0; r < 4; ++r)
                Os[(ni * 16 + g * 4 + r) * XS_STRIDE + wid * 32 + dh * 16 + l15] = f2bf(oacc[dh][r]);
    }
    __syncthreads();

    // ---- phase 5: Y = Os @ Wo + bo, f32 store ----
    {
        f32x4 yacc[4][2] = {{fz, fz}, {fz, fz}, {fz, fz}, {fz, fz}};
#pragma unroll
        for (int kk = 0; kk < 8; ++kk) {
            bf16x8 a[4], b[2];
#pragma unroll
            for (int mi = 0; mi < 4; ++mi)
                a[mi] = *reinterpret_cast<const bf16x8*>(&Os[(mi * 16 + l15) * XS_STRIDE + kk * 32 + g * 8]);
#pragma unroll
            for (int ni = 0; ni < 2; ++ni)
                b[ni] = *reinterpret_cast<const bf16x8*>(&WO[(wid * 32 + ni * 16 + l15) * 256 + kk * 32 + g * 8]);
#pragma unroll
            for (int mi = 0; mi < 4; ++mi)
#pragma unroll
                for (int ni = 0; ni < 2; ++ni)
                    yacc[mi][ni] = mfma_bf16(a[mi], b[ni], yacc[mi][ni]);
        }
#pragma unroll
        for (int mi = 0; mi < 4; ++mi) {
#pragma unroll
            for (int ni = 0; ni < 2; ++ni) {
                int col = wid * 32 + ni * 16 + l15;
                float bv = bo[col];
#pragma unroll
                for (int r = 0; r < 4; ++r) {
                    int row = mi * 16 + g * 4 + r;
                    out[(base_tok + row) * 256 + col] = yacc[mi][ni][r] + bv;
                }
            }
        }
    }
}

extern "C" void kernel_launch(void* const* d_in, const int* in_sizes, int n_in,
                              void* d_out, int out_size, void* d_ws, size_t ws_size,
                              hipStream_t stream) {
    const float* x  = (const float*)d_in[0];
    const float* wq = (const float*)d_in[1];
    const float* wk = (const float*)d_in[2];
    const float* wv = (const float*)d_in[3];
    const float* wo = (const float*)d_in[4];
    const float* bo = (const float*)d_in[5];
    unsigned short* wt = (unsigned short*)d_ws;      // 4 * 256*256 bf16 = 512 KiB
    float* out = (float*)d_out;                      // f32 output

    prep_weights<<<64, 256, 0, stream>>>(wq, wk, wv, wo, wt);
    win_attn<<<1024, 512, 0, stream>>>(x, wt, bo, out);
}

// Round 9
// 78.099 us; speedup vs baseline: 1.4915x; 1.3785x over previous
//
#include <hip/hip_runtime.h>
#include <hip/hip_bf16.h>

typedef short bf16x8 __attribute__((ext_vector_type(8)));
typedef float f32x4  __attribute__((ext_vector_type(4)));

__device__ __forceinline__ unsigned short f2bf(float f) {
    union { __hip_bfloat16 b; unsigned short u; } v;
    v.b = __hip_bfloat16(f);          // native RNE cvt (pairs into v_cvt_pk_bf16_f32)
    return v.u;
}

__device__ __forceinline__ f32x4 mfma_bf16(bf16x8 a, bf16x8 b, f32x4 c) {
    return __builtin_amdgcn_mfma_f32_16x16x32_bf16(a, b, c, 0, 0, 0);
}

// pack two f32x4 acc tiles (m-tile 0, m-tile 1) into one bf16 fragment under
// the shared k-bijection pi(g,j) = {4g+j | j<4} u {16+4g+(j-4) | j>=4}
__device__ __forceinline__ bf16x8 pack2(f32x4 lo, f32x4 hi) {
    bf16x8 r;
    r[0] = (short)f2bf(lo[0]); r[1] = (short)f2bf(lo[1]);
    r[2] = (short)f2bf(lo[2]); r[3] = (short)f2bf(lo[3]);
    r[4] = (short)f2bf(hi[0]); r[5] = (short)f2bf(hi[1]);
    r[6] = (short)f2bf(hi[2]); r[7] = (short)f2bf(hi[3]);
    return r;
}

// ---------------- prep: weights -> MFMA-fragment-linear bf16 layout ----------------
// slot s = (((mat*8 + h)*2 + t)*8 + kk)*64 + lane ; each slot = 8 bf16 (16 B).
// content: W[k][n] for n = h*32 + t*16 + (lane&15), k = kk*32 + (lane>>4)*8 + j.
// A wave's fragment load is then ONE contiguous 1 KiB global_load_dwordx4 stream.
__global__ __launch_bounds__(256) void prep_weights(
    const float* __restrict__ wq, const float* __restrict__ wk,
    const float* __restrict__ wv, const float* __restrict__ wo,
    unsigned short* __restrict__ wt)
{
    const int s = blockIdx.x * 256 + threadIdx.x;   // 0..32767
    const int mat  = s >> 13;
    const int h    = (s >> 10) & 7;
    const int t    = (s >> 9) & 1;
    const int kk   = (s >> 6) & 7;
    const int lane = s & 63;
    const int l15  = lane & 15;
    const int g    = lane >> 4;
    const float* src = (mat == 0) ? wq : (mat == 1) ? wk : (mat == 2) ? wv : wo;
    const int n  = h * 32 + t * 16 + l15;
    const int k0 = kk * 32 + g * 8;
    unsigned short* dst = wt + (size_t)s * 8;
#pragma unroll
    for (int j = 0; j < 8; ++j)
        dst[j] = f2bf(src[(k0 + j) * 256 + n]);
}

// ---------------- fused window attention, register-resident attention ----------------
// grid = 1024 (= 16 b * 64 h), block = 512 (8 waves). Each WG owns 64 tokens.
// wave w = head w. V, Q^T, K^T computed in ONE merged kk-loop (24 independent
// MFMAs/kk, shared Xs reads, streaming fragment-linear W loads). Attention
// (S^T via swapped operands, softmax, PV) entirely in registers, per q-tile so
// P is only 8 regs at a time (r7/r8 lesson). 2 barriers. No spill at (512,2).
#define XS_STRIDE 264   // 256 + 8 pad shorts

__global__ __launch_bounds__(512, 2) void win_attn(
    const float* __restrict__ x,
    const unsigned short* __restrict__ wt,   // fragment-linear weights (512 KiB)
    const float* __restrict__ bo,
    float* __restrict__ out)                 // f32 output
{
    __shared__ unsigned short lds[33792];    // 66 KiB
    unsigned short* Xs = lds;                // [64][264]
    unsigned short* Os = lds + 16896;        // [64][264]

    const int tid  = threadIdx.x;
    const int wid  = tid >> 6;               // 0..7 (= head)
    const int lane = tid & 63;
    const int l15  = lane & 15;
    const int g    = lane >> 4;              // 0..3

    const bf16x8* WF = reinterpret_cast<const bf16x8*>(wt);
    // fragment index: (((mat*8 + wid)*2 + t)*8 + kk)*64 + lane
    const int wbase = (wid * 2) * 8 * 64 + lane;          // per-mat offset added below
#define WFRAG(mat, t, kk) WF[(mat) * 8192 + wbase + ((t) * 8 + (kk)) * 64]

    const long long base_tok = (long long)blockIdx.x * 64;
    const float* xblk = x + base_tok * 256;

    const f32x4 fz = {0.f, 0.f, 0.f, 0.f};

    // ---- phase 0: stage x row-block as bf16 in LDS ----
#pragma unroll
    for (int i = 0; i < 8; ++i) {
        int p   = tid + i * 512;             // float4 index, 0..4095
        int tok = p >> 6;
        int col = (p & 63) * 4;
        float4 v = reinterpret_cast<const float4*>(xblk)[p];
        ushort4 h;
        h.x = f2bf(v.x); h.y = f2bf(v.y); h.z = f2bf(v.z); h.w = f2bf(v.w);
        *reinterpret_cast<ushort4*>(&Xs[tok * XS_STRIDE + col]) = h;
    }
    __syncthreads();

    // ---- phase 1: merged V / Q^T / K^T projections (one kk loop, 24 MFMA/kk) ----
    // Q^T,K^T: A = W-frag (m=d), B = Xs rows (n=token) -> lane: token=nt*16+l15, d=mt*16+4g+r
    // V:       A = Xs rows (m=token), B = Wv-frag (n=d) -> lane: d=dh*16+l15, token=mi*16+4g+r
    bf16x8 qtf[4], ktf[4], vtf[2][2];
    {
        f32x4 qt[2][4] = {{fz, fz, fz, fz}, {fz, fz, fz, fz}};
        f32x4 kt[2][4] = {{fz, fz, fz, fz}, {fz, fz, fz, fz}};
        f32x4 vac[4][2] = {{fz, fz}, {fz, fz}, {fz, fz}, {fz, fz}};
#pragma unroll
        for (int kk = 0; kk < 8; ++kk) {
            bf16x8 bx[4];
#pragma unroll
            for (int nt = 0; nt < 4; ++nt)
                bx[nt] = *reinterpret_cast<const bf16x8*>(&Xs[(nt * 16 + l15) * XS_STRIDE + kk * 32 + g * 8]);
            bf16x8 awq[2], awk[2], bv[2];
#pragma unroll
            for (int t = 0; t < 2; ++t) {
                awq[t] = WFRAG(0, t, kk);
                awk[t] = WFRAG(1, t, kk);
                bv[t]  = WFRAG(2, t, kk);
            }
#pragma unroll
            for (int mt = 0; mt < 2; ++mt)
#pragma unroll
                for (int nt = 0; nt < 4; ++nt) {
                    qt[mt][nt] = mfma_bf16(awq[mt], bx[nt], qt[mt][nt]);
                    kt[mt][nt] = mfma_bf16(awk[mt], bx[nt], kt[mt][nt]);
                }
#pragma unroll
            for (int mi = 0; mi < 4; ++mi)
#pragma unroll
                for (int dh = 0; dh < 2; ++dh)
                    vac[mi][dh] = mfma_bf16(bx[mi], bv[dh], vac[mi][dh]);
        }
#pragma unroll
        for (int nt = 0; nt < 4; ++nt) {
            qtf[nt] = pack2(qt[0][nt], qt[1][nt]);
            ktf[nt] = pack2(kt[0][nt], kt[1][nt]);
        }
#pragma unroll
        for (int dh = 0; dh < 2; ++dh) {
            vtf[0][dh] = pack2(vac[0][dh], vac[1][dh]);
            vtf[1][dh] = pack2(vac[2][dh], vac[3][dh]);
        }
    }

    // ---- phase 2: per q-tile ni: S^T = K Q^T, softmax over k_tok, pa, PV, Os ----
    // st[mi]: lane -> k_tok = mi*16 + 4g + r, q = ni*16 + l15
    constexpr float kC = 0.25501817419392105f;  // (1/sqrt(32)) * log2(e)
#pragma unroll
    for (int ni = 0; ni < 4; ++ni) {
        f32x4 st[4];
#pragma unroll
        for (int mi = 0; mi < 4; ++mi)
            st[mi] = mfma_bf16(ktf[mi], qtf[ni], fz);
        float m = st[0][0];
#pragma unroll
        for (int mi = 0; mi < 4; ++mi)
#pragma unroll
            for (int r = 0; r < 4; ++r) m = fmaxf(m, st[mi][r]);
        m = fmaxf(m, __shfl_xor(m, 16));
        m = fmaxf(m, __shfl_xor(m, 32));
        float sum = 0.f;
#pragma unroll
        for (int mi = 0; mi < 4; ++mi)
#pragma unroll
            for (int r = 0; r < 4; ++r) {
                st[mi][r] = exp2f((st[mi][r] - m) * kC);   // in place
                sum += st[mi][r];
            }
        sum += __shfl_xor(sum, 16);
        sum += __shfl_xor(sum, 32);
        float inv = 1.0f / sum;
        bf16x8 pa[2];                            // P fragment for THIS q-tile only
#pragma unroll
        for (int kk = 0; kk < 2; ++kk) {
            bf16x8 t;
#pragma unroll
            for (int j = 0; j < 4; ++j) {
                t[j]     = (short)f2bf(st[2 * kk][j] * inv);
                t[4 + j] = (short)f2bf(st[2 * kk + 1][j] * inv);
            }
            pa[kk] = t;
        }
        f32x4 oacc[2] = {fz, fz};
#pragma unroll
        for (int kk = 0; kk < 2; ++kk)
#pragma unroll
            for (int dh = 0; dh < 2; ++dh)
                oacc[dh] = mfma_bf16(pa[kk], vtf[kk][dh], oacc[dh]);
#pragma unroll
        for (int dh = 0; dh < 2; ++dh)
#pragma unroll
            for (int r = 0; r < 4; ++r)
                Os[(ni * 16 + g * 4 + r) * XS_STRIDE + wid * 32 + dh * 16 + l15] = f2bf(oacc[dh][r]);
    }
    __syncthreads();

    // ---- phase 3: Y = Os @ Wo + bo, f32 store ----
    {
        f32x4 yacc[4][2] = {{fz, fz}, {fz, fz}, {fz, fz}, {fz, fz}};
#pragma unroll
        for (int kk = 0; kk < 8; ++kk) {
            bf16x8 a[4], b[2];
#pragma unroll
            for (int ni = 0; ni < 2; ++ni)
                b[ni] = WFRAG(3, ni, kk);
#pragma unroll
            for (int mi = 0; mi < 4; ++mi)
                a[mi] = *reinterpret_cast<const bf16x8*>(&Os[(mi * 16 + l15) * XS_STRIDE + kk * 32 + g * 8]);
#pragma unroll
            for (int mi = 0; mi < 4; ++mi)
#pragma unroll
                for (int ni = 0; ni < 2; ++ni)
                    yacc[mi][ni] = mfma_bf16(a[mi], b[ni], yacc[mi][ni]);
        }
#pragma unroll
        for (int mi = 0; mi < 4; ++mi) {
#pragma unroll
            for (int ni = 0; ni < 2; ++ni) {
                int col = wid * 32 + ni * 16 + l15;
                float bv = bo[col];
#pragma unroll
                for (int r = 0; r < 4; ++r) {
                    int row = mi * 16 + g * 4 + r;
                    out[(base_tok + row) * 256 + col] = yacc[mi][ni][r] + bv;
                }
            }
        }
    }
#undef WFRAG
}

extern "C" void kernel_launch(void* const* d_in, const int* in_sizes, int n_in,
                              void* d_out, int out_size, void* d_ws, size_t ws_size,
                              hipStream_t stream) {
    const float* x  = (const float*)d_in[0];
    const float* wq = (const float*)d_in[1];
    const float* wk = (const float*)d_in[2];
    const float* wv = (const float*)d_in[3];
    const float* wo = (const float*)d_in[4];
    const float* bo = (const float*)d_in[5];
    unsigned short* wt = (unsigned short*)d_ws;      // 4 * 256*256 bf16 = 512 KiB
    float* out = (float*)d_out;                      // f32 output

    prep_weights<<<128, 256, 0, stream>>>(wq, wk, wv, wo, wt);
    win_attn<<<1024, 512, 0, stream>>>(x, wt, bo, out);
}